// Round 2
// baseline (2636.868 us; speedup 1.0000x reference)
//
#include <hip/hip_runtime.h>
#include <math.h>
#include <float.h>

#define N_ROWS 32768
#define D_DIM  256
#define K_DIM  8192
#define GAP_EPS 0.0625f

// ---------------------------------------------------------------------------
// Kernel 1: enorm[k] = sum_d E[d][k]^2
// ---------------------------------------------------------------------------
__global__ void enorm_kernel(const float* __restrict__ E, float* __restrict__ enorm) {
    int k = blockIdx.x * 256 + threadIdx.x;
    float s = 0.0f;
#pragma unroll 8
    for (int d = 0; d < D_DIM; ++d) {
        float v = E[(size_t)d * K_DIM + k];
        s = fmaf(v, v, s);
    }
    enorm[k] = s;
}

// ---------------------------------------------------------------------------
// Kernel 2: fused distance + top-2 argmin (fp32 pass).
// Block = 64 rows x all K. 256 threads: ty=tid>>4 (row-group of 4 rows),
// tx=tid&15 (k-group of 4 cols). 4x4 register tile per thread.
// Emits per-row best idx + gap to 2nd-best for the fp64 refine pass.
// ---------------------------------------------------------------------------
__launch_bounds__(256, 2)
__global__ void dist_argmin_kernel(const float* __restrict__ X,
                                   const float* __restrict__ E,
                                   const float* __restrict__ enorm,
                                   int* __restrict__ idx_out,
                                   float* __restrict__ gap_out) {
    __shared__ float xT[D_DIM][64];   // xT[d][r]
    __shared__ float es[64][64];      // es[d'][k']

    const int tid = threadIdx.x;
    const int tx = tid & 15;
    const int ty = tid >> 4;
    const int rowBase = blockIdx.x * 64;

    // Stage X rows transposed.
    {
        const int r  = tid >> 2;
        const int d0 = (tid & 3) * 64;
        const float* xp = X + (size_t)(rowBase + r) * D_DIM + d0;
#pragma unroll
        for (int i = 0; i < 64; i += 4) {
            float4 v = *reinterpret_cast<const float4*>(xp + i);
            xT[d0 + i + 0][r] = v.x;
            xT[d0 + i + 1][r] = v.y;
            xT[d0 + i + 2][r] = v.z;
            xT[d0 + i + 3][r] = v.w;
        }
    }

    float bestVal[4], secVal[4];
    int   bestIdx[4];
#pragma unroll
    for (int i = 0; i < 4; ++i) {
        bestVal[i] = INFINITY; secVal[i] = INFINITY; bestIdx[i] = 0;
    }

    for (int kc = 0; kc < K_DIM; kc += 64) {
        float acc[4][4];
#pragma unroll
        for (int i = 0; i < 4; ++i)
#pragma unroll
            for (int j = 0; j < 4; ++j) acc[i][j] = 0.0f;

        for (int dc = 0; dc < D_DIM; dc += 64) {
            __syncthreads();   // es reuse fence (and xT visibility on first iter)
#pragma unroll
            for (int dd = 0; dd < 64; dd += 16) {
                int d = dd + (tid >> 4);
                float4 v = *reinterpret_cast<const float4*>(
                    &E[(size_t)(dc + d) * K_DIM + kc + (tid & 15) * 4]);
                *reinterpret_cast<float4*>(&es[d][(tid & 15) * 4]) = v;
            }
            __syncthreads();

#pragma unroll 8
            for (int d = 0; d < 64; ++d) {
                float4 xv = *reinterpret_cast<const float4*>(&xT[dc + d][ty * 4]);
                float4 ev = *reinterpret_cast<const float4*>(&es[d][tx * 4]);
                float xr[4] = {xv.x, xv.y, xv.z, xv.w};
                float ec[4] = {ev.x, ev.y, ev.z, ev.w};
#pragma unroll
                for (int i = 0; i < 4; ++i)
#pragma unroll
                    for (int j = 0; j < 4; ++j)
                        acc[i][j] = fmaf(xr[i], ec[j], acc[i][j]);
            }
        }

        // Score + running top-2. k ascending; strict < keeps first index.
        float4 env = *reinterpret_cast<const float4*>(&enorm[kc + tx * 4]);
        float en[4] = {env.x, env.y, env.z, env.w};
#pragma unroll
        for (int j = 0; j < 4; ++j) {
            int k = kc + tx * 4 + j;
#pragma unroll
            for (int i = 0; i < 4; ++i) {
                float s = fmaf(-2.0f, acc[i][j], en[j]);
                if (s < bestVal[i]) {
                    secVal[i] = bestVal[i];
                    bestVal[i] = s;
                    bestIdx[i] = k;
                } else if (s < secVal[i]) {
                    secVal[i] = s;
                }
            }
        }
    }

    // Top-2 merge across the 16 tx lanes (lanes ty*16..ty*16+15, in-wave).
#pragma unroll
    for (int off = 8; off >= 1; off >>= 1) {
#pragma unroll
        for (int i = 0; i < 4; ++i) {
            float oB = __shfl_xor(bestVal[i], off, 16);
            int   oI = __shfl_xor(bestIdx[i], off, 16);
            float oS = __shfl_xor(secVal[i], off, 16);
            float mergedSec = fminf(fminf(secVal[i], oS), fmaxf(bestVal[i], oB));
            if (oB < bestVal[i] || (oB == bestVal[i] && oI < bestIdx[i])) {
                bestVal[i] = oB;
                bestIdx[i] = oI;
            }
            secVal[i] = mergedSec;
        }
    }
    if (tx == 0) {
#pragma unroll
        for (int i = 0; i < 4; ++i) {
            idx_out[rowBase + ty * 4 + i] = bestIdx[i];
            gap_out[rowBase + ty * 4 + i] = secVal[i] - bestVal[i];
        }
    }
}

// ---------------------------------------------------------------------------
// Kernel 3: fp64 refine for knife-edge rows (gap < GAP_EPS). One block per
// row; non-flagged blocks exit immediately. ~200 rows expected.
// ---------------------------------------------------------------------------
__launch_bounds__(256)
__global__ void refine_kernel(const float* __restrict__ X,
                              const float* __restrict__ E,
                              const float* __restrict__ gap,
                              int* __restrict__ idx) {
    const int n = blockIdx.x;
    if (gap[n] >= GAP_EPS) return;   // uniform branch

    __shared__ float xs[D_DIM];
    const int tid = threadIdx.x;
    xs[tid] = X[(size_t)n * D_DIM + tid];
    __syncthreads();

    double best = DBL_MAX;
    int bi = 0x7fffffff;
    for (int k = tid; k < K_DIM; k += 256) {
        double s0 = 0.0, s1 = 0.0, s2 = 0.0, s3 = 0.0;
#pragma unroll 4
        for (int d = 0; d < D_DIM; d += 4) {
            double f0 = (double)xs[d + 0] - (double)E[(size_t)(d + 0) * K_DIM + k];
            double f1 = (double)xs[d + 1] - (double)E[(size_t)(d + 1) * K_DIM + k];
            double f2 = (double)xs[d + 2] - (double)E[(size_t)(d + 2) * K_DIM + k];
            double f3 = (double)xs[d + 3] - (double)E[(size_t)(d + 3) * K_DIM + k];
            s0 = fma(f0, f0, s0); s1 = fma(f1, f1, s1);
            s2 = fma(f2, f2, s2); s3 = fma(f3, f3, s3);
        }
        double s = (s0 + s1) + (s2 + s3);
        if (s < best) { best = s; bi = k; }
    }

    __shared__ double bv[256];
    __shared__ int    bix[256];
    bv[tid] = best; bix[tid] = bi;
    __syncthreads();
    if (tid == 0) {
        double b = bv[0]; int ix = bix[0];
        for (int t = 1; t < 256; ++t) {
            if (bv[t] < b || (bv[t] == b && bix[t] < ix)) { b = bv[t]; ix = bix[t]; }
        }
        idx[n] = ix;
    }
}

// ---------------------------------------------------------------------------
// Kernel 4: gather — out[n][d] = E[d][idx[n]]
// ---------------------------------------------------------------------------
__global__ void gather_kernel(const float* __restrict__ E,
                              const int* __restrict__ idx,
                              float* __restrict__ out) {
    const int n = blockIdx.x;
    const int d = threadIdx.x;
    const int k = idx[n];
    out[(size_t)n * D_DIM + d] = E[(size_t)d * K_DIM + k];
}

// ---------------------------------------------------------------------------
extern "C" void kernel_launch(void* const* d_in, const int* in_sizes, int n_in,
                              void* d_out, int out_size, void* d_ws, size_t ws_size,
                              hipStream_t stream) {
    const float* X = (const float*)d_in[0];        // [N, D]
    const float* E = (const float*)d_in[1];        // [D, K]
    float* out = (float*)d_out;                    // [N, D]

    float* enorm = (float*)d_ws;                                    // K floats
    int*   idx   = (int*)((char*)d_ws + (size_t)K_DIM * 4);         // N ints
    float* gap   = (float*)((char*)d_ws + (size_t)K_DIM * 4
                                        + (size_t)N_ROWS * 4);      // N floats

    enorm_kernel<<<K_DIM / 256, 256, 0, stream>>>(E, enorm);
    dist_argmin_kernel<<<N_ROWS / 64, 256, 0, stream>>>(X, E, enorm, idx, gap);
    refine_kernel<<<N_ROWS, 256, 0, stream>>>(X, E, gap, idx);
    gather_kernel<<<N_ROWS, 256, 0, stream>>>(E, idx, out);
}

// Round 3
// 687.456 us; speedup vs baseline: 3.8357x; 3.8357x over previous
//
#include <hip/hip_runtime.h>
#include <math.h>
#include <float.h>

#define N_ROWS 32768
#define D_DIM  256
#define K_DIM  8192

#define EPS1 0.40f   // tier-1 (f16) gap threshold, full-distance scale
#define EPS2 0.02f   // tier-2 (fp32) gap threshold
#define T2CAP 4096   // tier-2 row capacity

typedef _Float16 f16;
typedef _Float16 f16x8 __attribute__((ext_vector_type(8)));
typedef float f32x4 __attribute__((ext_vector_type(4)));

#define KSPLIT 4
#define COLS_PER_SPLIT (K_DIM / KSPLIT)     // 2048
#define CHUNK_COLS 32
#define NCHUNK (COLS_PER_SPLIT / CHUNK_COLS) // 64

// ---------------------------------------------------------------------------
// convert X fp32 -> f16, [N][D] row-major. 8 elems/thread.
// ---------------------------------------------------------------------------
__global__ void convx_kernel(const float* __restrict__ X, f16* __restrict__ X16) {
    const size_t i = ((size_t)blockIdx.x * 256 + threadIdx.x) * 8;
    float4 a = *reinterpret_cast<const float4*>(X + i);
    float4 b = *reinterpret_cast<const float4*>(X + i + 4);
    f16x8 o;
    o[0]=(f16)a.x; o[1]=(f16)a.y; o[2]=(f16)a.z; o[3]=(f16)a.w;
    o[4]=(f16)b.x; o[5]=(f16)b.y; o[6]=(f16)b.z; o[7]=(f16)b.w;
    *reinterpret_cast<f16x8*>(X16 + i) = o;
}

// ---------------------------------------------------------------------------
// pack E fp32 [D][K] -> Epack f16 in B-fragment-linear order.
// B-frag (16x16x32): lane l, elem j  <-  E[32t + (l>>4)*8 + j][16*tile + (l&15)]
// Epack[(tile*8 + t)*512 + l*8 + j]
// thread = (tile,t,l): 8 strided reads, one 16B store.
// ---------------------------------------------------------------------------
__global__ void packe_kernel(const float* __restrict__ E, f16* __restrict__ Epack) {
    const int gid = blockIdx.x * 256 + threadIdx.x;  // 512*8*64 = 262144
    const int l    = gid & 63;
    const int t    = (gid >> 6) & 7;
    const int tile = gid >> 9;
    const int k  = 16 * tile + (l & 15);
    const int d0 = 32 * t + (l >> 4) * 8;
    f16x8 o;
#pragma unroll
    for (int j = 0; j < 8; ++j) o[j] = (f16)E[(size_t)(d0 + j) * K_DIM + k];
    *reinterpret_cast<f16x8*>(Epack + (size_t)gid * 8) = o;
}

// ---------------------------------------------------------------------------
// nhen[k] = -0.5 * sum_d E[d][k]^2   (fp32)
// ---------------------------------------------------------------------------
__global__ void nhen_kernel(const float* __restrict__ E, float* __restrict__ nhen) {
    const int k = blockIdx.x * 256 + threadIdx.x;
    float s = 0.0f;
#pragma unroll 8
    for (int d = 0; d < D_DIM; ++d) {
        float v = E[(size_t)d * K_DIM + k];
        s = fmaf(v, v, s);
    }
    nhen[k] = -0.5f * s;
}

// ---------------------------------------------------------------------------
// pass1: f16 MFMA fused GEMM + per-row top-2 argmax of u = x.e - 0.5||e||^2
// (argmax u == argmin squared distance). Block: 4 waves x 64 rows = 256 rows,
// K-split 4 (2048 cols each). A (X rows) resident in VGPRs; B (E) staged in
// LDS double-buffered, frag-linear; acc init = nhen (folds epilogue).
// ---------------------------------------------------------------------------
__launch_bounds__(256, 2)
__global__ void pass1_kernel(const f16* __restrict__ X16,
                             const f16* __restrict__ Epack,
                             const float* __restrict__ nhen,
                             float* __restrict__ p_best,
                             float* __restrict__ p_sec,
                             int*   __restrict__ p_idx) {
    __shared__ f16 B_lds[2][8192];   // 2 x 16KB (32 cols x 256 d)

    const int tid = threadIdx.x;
    const int wv = tid >> 6;
    const int lane = tid & 63;
    const int l15 = lane & 15;
    const int l4  = lane >> 4;
    const int rg = blockIdx.x >> 2;
    const int ks = blockIdx.x & 3;
    const int rowW = rg * 256 + wv * 64;
    const int colBase = ks * COLS_PER_SPLIT;

    // A fragments: rows rowW..rowW+63, full D. A[rt][t]: lane l -> row rowW+16rt+(l&15),
    // d = 32t + (l>>4)*8 + j  (16B contiguous)
    f16x8 A[4][8];
#pragma unroll
    for (int rt = 0; rt < 4; ++rt)
#pragma unroll
        for (int t = 0; t < 8; ++t)
            A[rt][t] = *reinterpret_cast<const f16x8*>(
                X16 + (size_t)(rowW + 16*rt + l15) * D_DIM + 32*t + l4*8);

    float best[16], sec[16];
    int bbase[16];
#pragma unroll
    for (int s = 0; s < 16; ++s) { best[s] = -INFINITY; sec[s] = -INFINITY; bbase[s] = 0; }

    // chunk source: 16KB contiguous per 32-col chunk (frag-linear pack)
    const float4* src = reinterpret_cast<const float4*>(
        Epack + (size_t)(ks * 128) * 8 * 512);

    float4 sreg[4];
    // prolog: stage chunk 0 into buf 0
#pragma unroll
    for (int q = 0; q < 4; ++q) sreg[q] = src[q*256 + tid];
    {
        float4* bw = reinterpret_cast<float4*>(&B_lds[0][0]);
#pragma unroll
        for (int q = 0; q < 4; ++q) bw[q*256 + tid] = sreg[q];
    }

    for (int ci = 0; ci < NCHUNK; ++ci) {
        __syncthreads();   // buf[ci&1] visible; prev readers of buf[(ci+1)&1] done
        if (ci + 1 < NCHUNK) {
#pragma unroll
            for (int q = 0; q < 4; ++q)
                sreg[q] = src[(size_t)(ci+1)*1024 + q*256 + tid];
        }
        const f16* bufc = &B_lds[ci & 1][0];
        const int c0 = colBase + ci * CHUNK_COLS;

#pragma unroll
        for (int ct = 0; ct < 2; ++ct) {
            const float nh = nhen[c0 + 16*ct + l15];
            const f32x4 nh4 = {nh, nh, nh, nh};
            f32x4 acc[4];
            {
                f16x8 B = *reinterpret_cast<const f16x8*>(bufc + (ct*8)*512 + lane*8);
#pragma unroll
                for (int rt = 0; rt < 4; ++rt)
                    acc[rt] = __builtin_amdgcn_mfma_f32_16x16x32_f16(A[rt][0], B, nh4, 0, 0, 0);
            }
#pragma unroll
            for (int t = 1; t < 8; ++t) {
                f16x8 B = *reinterpret_cast<const f16x8*>(bufc + (ct*8 + t)*512 + lane*8);
#pragma unroll
                for (int rt = 0; rt < 4; ++rt)
                    acc[rt] = __builtin_amdgcn_mfma_f32_16x16x32_f16(A[rt][t], B, acc[rt], 0, 0, 0);
            }
            // scoring: track top-2 max of acc (strict > keeps first k on ties)
#pragma unroll
            for (int rt = 0; rt < 4; ++rt) {
#pragma unroll
                for (int r = 0; r < 4; ++r) {
                    const float v = acc[rt][r];
                    const int sl = rt*4 + r;
                    const bool gt = v > best[sl];
                    sec[sl]  = fmaxf(sec[sl], fminf(v, best[sl]));
                    best[sl] = gt ? v : best[sl];
                    bbase[sl] = gt ? (c0 + 16*ct) : bbase[sl];
                }
            }
        }

        if (ci + 1 < NCHUNK) {
            float4* bw = reinterpret_cast<float4*>(&B_lds[(ci+1) & 1][0]);
#pragma unroll
            for (int q = 0; q < 4; ++q) bw[q*256 + tid] = sreg[q];
        }
    }

    // reduce top-2 across the 16 lanes (l15) of each quarter-wave
#pragma unroll
    for (int s = 0; s < 16; ++s) {
        float b = best[s], sc = sec[s];
        int k = bbase[s] + l15;
#pragma unroll
        for (int off = 8; off >= 1; off >>= 1) {
            float ob = __shfl_xor(b, off, 16);
            float os = __shfl_xor(sc, off, 16);
            int   ok = __shfl_xor(k, off, 16);
            float sm = fmaxf(fmaxf(sc, os), fminf(b, ob));
            bool take = (ob > b) || (ob == b && ok < k);
            b = take ? ob : b;
            k = take ? ok : k;
            sc = sm;
        }
        if (l15 == 0) {
            const int row = rowW + 16*(s >> 2) + 4*l4 + (s & 3);
            p_best[ks * N_ROWS + row] = b;
            p_sec [ks * N_ROWS + row] = sc;
            p_idx [ks * N_ROWS + row] = k;
        }
    }
}

// ---------------------------------------------------------------------------
__global__ void zero_count_kernel(int* count) { *count = 0; }

// merge K-splits; flag rows with gap < EPS1 into compacted list
__global__ void merge_kernel(const float* __restrict__ p_best,
                             const float* __restrict__ p_sec,
                             const int*   __restrict__ p_idx,
                             int* __restrict__ idxf, float* __restrict__ gap2,
                             int* __restrict__ list, int* __restrict__ count) {
    const int n = blockIdx.x * 256 + threadIdx.x;
    float b = p_best[n], sc = p_sec[n];
    int k = p_idx[n];
#pragma unroll
    for (int s = 1; s < KSPLIT; ++s) {
        float ob = p_best[s * N_ROWS + n];
        float os = p_sec [s * N_ROWS + n];
        int   ok = p_idx [s * N_ROWS + n];
        float sm = fmaxf(fmaxf(sc, os), fminf(b, ob));
        bool take = ob > b;            // equal -> keep earlier split (smaller k)
        b = take ? ob : b; k = take ? ok : k; sc = sm;
    }
    idxf[n] = k;
    gap2[n] = 1e30f;
    if (2.0f * (b - sc) < EPS1) {
        int pos = atomicAdd(count, 1);
        if (pos < T2CAP) list[pos] = n;
    }
}

// ---------------------------------------------------------------------------
// tier-2: fp32 rescan of flagged rows. Block = (group of 64 rows) x (512-col
// split). Tracks top-2 max of u = dot + nhen.
// ---------------------------------------------------------------------------
__launch_bounds__(256, 2)
__global__ void tier2_kernel(const float* __restrict__ X,
                             const float* __restrict__ E,
                             const float* __restrict__ nhen,
                             const int* __restrict__ list,
                             const int* __restrict__ count,
                             float* __restrict__ t2b, float* __restrict__ t2s,
                             int* __restrict__ t2i) {
    const int g  = blockIdx.x >> 4;
    const int sp = blockIdx.x & 15;
    const int cnt = min(*count, T2CAP);
    if (g * 64 >= cnt) return;

    __shared__ float xT[D_DIM][64];
    __shared__ float es[64][64];
    const int tid = threadIdx.x;
    const int tx = tid & 15, ty = tid >> 4;

    {
        const int r = tid >> 2;
        const int slot = min(g * 64 + r, cnt - 1);
        const int row = list[slot];
        const int d0 = (tid & 3) * 64;
        const float* xp = X + (size_t)row * D_DIM + d0;
#pragma unroll
        for (int i = 0; i < 64; i += 4) {
            float4 v = *reinterpret_cast<const float4*>(xp + i);
            xT[d0+i+0][r] = v.x; xT[d0+i+1][r] = v.y;
            xT[d0+i+2][r] = v.z; xT[d0+i+3][r] = v.w;
        }
    }

    float best[4], sec[4]; int bidx[4];
#pragma unroll
    for (int i = 0; i < 4; ++i) { best[i] = -INFINITY; sec[i] = -INFINITY; bidx[i] = 0; }

    const int colBase = sp * 512;
    for (int kc = 0; kc < 512; kc += 64) {
        float acc[4][4];
#pragma unroll
        for (int i = 0; i < 4; ++i)
#pragma unroll
            for (int j = 0; j < 4; ++j) acc[i][j] = 0.0f;

        for (int dc = 0; dc < D_DIM; dc += 64) {
            __syncthreads();
#pragma unroll
            for (int dd = 0; dd < 64; dd += 16) {
                int d = dd + (tid >> 4);
                float4 v = *reinterpret_cast<const float4*>(
                    &E[(size_t)(dc + d) * K_DIM + colBase + kc + (tid & 15) * 4]);
                *reinterpret_cast<float4*>(&es[d][(tid & 15) * 4]) = v;
            }
            __syncthreads();
#pragma unroll 8
            for (int d = 0; d < 64; ++d) {
                float4 xv = *reinterpret_cast<const float4*>(&xT[dc + d][ty * 4]);
                float4 ev = *reinterpret_cast<const float4*>(&es[d][tx * 4]);
                float xr[4] = {xv.x, xv.y, xv.z, xv.w};
                float ec[4] = {ev.x, ev.y, ev.z, ev.w};
#pragma unroll
                for (int i = 0; i < 4; ++i)
#pragma unroll
                    for (int j = 0; j < 4; ++j)
                        acc[i][j] = fmaf(xr[i], ec[j], acc[i][j]);
            }
        }
        float4 nhv = *reinterpret_cast<const float4*>(&nhen[colBase + kc + tx * 4]);
        float nh[4] = {nhv.x, nhv.y, nhv.z, nhv.w};
#pragma unroll
        for (int j = 0; j < 4; ++j) {
            const int k = colBase + kc + tx * 4 + j;
#pragma unroll
            for (int i = 0; i < 4; ++i) {
                float u = nh[j] + acc[i][j];
                bool gt = u > best[i];
                sec[i]  = fmaxf(sec[i], fminf(u, best[i]));
                best[i] = gt ? u : best[i];
                bidx[i] = gt ? k : bidx[i];
            }
        }
    }

#pragma unroll
    for (int off = 8; off >= 1; off >>= 1) {
#pragma unroll
        for (int i = 0; i < 4; ++i) {
            float ob = __shfl_xor(best[i], off, 16);
            float os = __shfl_xor(sec[i], off, 16);
            int   ok = __shfl_xor(bidx[i], off, 16);
            float sm = fmaxf(fmaxf(sec[i], os), fminf(best[i], ob));
            bool take = (ob > best[i]) || (ob == best[i] && ok < bidx[i]);
            best[i] = take ? ob : best[i];
            bidx[i] = take ? ok : bidx[i];
            sec[i] = sm;
        }
    }
    if (tx == 0) {
#pragma unroll
        for (int i = 0; i < 4; ++i) {
            const int slot = g * 64 + ty * 4 + i;
            if (slot < cnt) {
                t2b[sp * T2CAP + slot] = best[i];
                t2s[sp * T2CAP + slot] = sec[i];
                t2i[sp * T2CAP + slot] = bidx[i];
            }
        }
    }
}

__global__ void merge2_kernel(const float* __restrict__ t2b,
                              const float* __restrict__ t2s,
                              const int*   __restrict__ t2i,
                              const int* __restrict__ list,
                              const int* __restrict__ count,
                              int* __restrict__ idxf, float* __restrict__ gap2) {
    const int slot = blockIdx.x * 256 + threadIdx.x;
    const int cnt = min(*count, T2CAP);
    if (slot >= cnt) return;
    float b = t2b[slot], sc = t2s[slot];
    int k = t2i[slot];
#pragma unroll
    for (int sp = 1; sp < 16; ++sp) {
        float ob = t2b[sp * T2CAP + slot];
        float os = t2s[sp * T2CAP + slot];
        int   ok = t2i[sp * T2CAP + slot];
        float sm = fmaxf(fmaxf(sc, os), fminf(b, ob));
        bool take = ob > b;
        b = take ? ob : b; k = take ? ok : k; sc = sm;
    }
    const int n = list[slot];
    idxf[n] = k;
    gap2[n] = 2.0f * (b - sc);
}

// ---------------------------------------------------------------------------
// tier-3: fp64 exact rescan for gap2 < EPS2 rows.
// ---------------------------------------------------------------------------
__launch_bounds__(256)
__global__ void tier3_kernel(const float* __restrict__ X,
                             const float* __restrict__ E,
                             const float* __restrict__ gap2,
                             int* __restrict__ idxf) {
    const int n = blockIdx.x;
    if (gap2[n] >= EPS2) return;

    __shared__ float xs[D_DIM];
    const int tid = threadIdx.x;
    xs[tid] = X[(size_t)n * D_DIM + tid];
    __syncthreads();

    double best = DBL_MAX;
    int bi = 0x7fffffff;
    for (int k = tid; k < K_DIM; k += 256) {
        double s0 = 0.0, s1 = 0.0, s2 = 0.0, s3 = 0.0;
#pragma unroll 4
        for (int d = 0; d < D_DIM; d += 4) {
            double f0 = (double)xs[d+0] - (double)E[(size_t)(d+0) * K_DIM + k];
            double f1 = (double)xs[d+1] - (double)E[(size_t)(d+1) * K_DIM + k];
            double f2 = (double)xs[d+2] - (double)E[(size_t)(d+2) * K_DIM + k];
            double f3 = (double)xs[d+3] - (double)E[(size_t)(d+3) * K_DIM + k];
            s0 = fma(f0, f0, s0); s1 = fma(f1, f1, s1);
            s2 = fma(f2, f2, s2); s3 = fma(f3, f3, s3);
        }
        double s = (s0 + s1) + (s2 + s3);
        if (s < best) { best = s; bi = k; }
    }
    __shared__ double bv[256];
    __shared__ int bix[256];
    bv[tid] = best; bix[tid] = bi;
    __syncthreads();
    if (tid == 0) {
        double b = bv[0]; int ix = bix[0];
        for (int t = 1; t < 256; ++t)
            if (bv[t] < b || (bv[t] == b && bix[t] < ix)) { b = bv[t]; ix = bix[t]; }
        idxf[n] = ix;
    }
}

// ---------------------------------------------------------------------------
__global__ void gather_kernel(const float* __restrict__ E,
                              const int* __restrict__ idx,
                              float* __restrict__ out) {
    const int n = blockIdx.x;
    const int d = threadIdx.x;
    const int k = idx[n];
    out[(size_t)n * D_DIM + d] = E[(size_t)d * K_DIM + k];
}

// ======================= fallback path (proven round-2) =====================
__global__ void fb_enorm_kernel(const float* __restrict__ E, float* __restrict__ enorm) {
    int k = blockIdx.x * 256 + threadIdx.x;
    float s = 0.0f;
#pragma unroll 8
    for (int d = 0; d < D_DIM; ++d) { float v = E[(size_t)d * K_DIM + k]; s = fmaf(v, v, s); }
    enorm[k] = s;
}

__launch_bounds__(256, 2)
__global__ void fb_dist_kernel(const float* __restrict__ X, const float* __restrict__ E,
                               const float* __restrict__ enorm,
                               int* __restrict__ idx_out, float* __restrict__ gap_out) {
    __shared__ float xT[D_DIM][64];
    __shared__ float es[64][64];
    const int tid = threadIdx.x;
    const int tx = tid & 15, ty = tid >> 4;
    const int rowBase = blockIdx.x * 64;
    {
        const int r = tid >> 2;
        const int d0 = (tid & 3) * 64;
        const float* xp = X + (size_t)(rowBase + r) * D_DIM + d0;
#pragma unroll
        for (int i = 0; i < 64; i += 4) {
            float4 v = *reinterpret_cast<const float4*>(xp + i);
            xT[d0+i+0][r]=v.x; xT[d0+i+1][r]=v.y; xT[d0+i+2][r]=v.z; xT[d0+i+3][r]=v.w;
        }
    }
    float bestVal[4], secVal[4]; int bestIdx[4];
#pragma unroll
    for (int i = 0; i < 4; ++i) { bestVal[i]=INFINITY; secVal[i]=INFINITY; bestIdx[i]=0; }
    for (int kc = 0; kc < K_DIM; kc += 64) {
        float acc[4][4];
#pragma unroll
        for (int i=0;i<4;++i)
#pragma unroll
            for (int j=0;j<4;++j) acc[i][j]=0.f;
        for (int dc = 0; dc < D_DIM; dc += 64) {
            __syncthreads();
#pragma unroll
            for (int dd = 0; dd < 64; dd += 16) {
                int d = dd + (tid >> 4);
                float4 v = *reinterpret_cast<const float4*>(
                    &E[(size_t)(dc+d)*K_DIM + kc + (tid&15)*4]);
                *reinterpret_cast<float4*>(&es[d][(tid&15)*4]) = v;
            }
            __syncthreads();
#pragma unroll 8
            for (int d = 0; d < 64; ++d) {
                float4 xv = *reinterpret_cast<const float4*>(&xT[dc+d][ty*4]);
                float4 ev = *reinterpret_cast<const float4*>(&es[d][tx*4]);
                float xr[4]={xv.x,xv.y,xv.z,xv.w}, ec[4]={ev.x,ev.y,ev.z,ev.w};
#pragma unroll
                for (int i=0;i<4;++i)
#pragma unroll
                    for (int j=0;j<4;++j) acc[i][j]=fmaf(xr[i],ec[j],acc[i][j]);
            }
        }
        float4 env = *reinterpret_cast<const float4*>(&enorm[kc + tx*4]);
        float en[4]={env.x,env.y,env.z,env.w};
#pragma unroll
        for (int j=0;j<4;++j) {
            int k = kc + tx*4 + j;
#pragma unroll
            for (int i=0;i<4;++i) {
                float s = fmaf(-2.0f, acc[i][j], en[j]);
                if (s < bestVal[i]) { secVal[i]=bestVal[i]; bestVal[i]=s; bestIdx[i]=k; }
                else if (s < secVal[i]) secVal[i]=s;
            }
        }
    }
#pragma unroll
    for (int off=8; off>=1; off>>=1) {
#pragma unroll
        for (int i=0;i<4;++i) {
            float oB=__shfl_xor(bestVal[i],off,16);
            int oI=__shfl_xor(bestIdx[i],off,16);
            float oS=__shfl_xor(secVal[i],off,16);
            float ms=fminf(fminf(secVal[i],oS),fmaxf(bestVal[i],oB));
            if (oB<bestVal[i] || (oB==bestVal[i] && oI<bestIdx[i])) { bestVal[i]=oB; bestIdx[i]=oI; }
            secVal[i]=ms;
        }
    }
    if (tx==0) {
#pragma unroll
        for (int i=0;i<4;++i) {
            idx_out[rowBase + ty*4 + i] = bestIdx[i];
            gap_out[rowBase + ty*4 + i] = secVal[i]-bestVal[i];
        }
    }
}

__launch_bounds__(256)
__global__ void fb_refine_kernel(const float* __restrict__ X, const float* __restrict__ E,
                                 const float* __restrict__ gap, int* __restrict__ idx) {
    const int n = blockIdx.x;
    if (gap[n] >= 0.0625f) return;
    __shared__ float xs[D_DIM];
    const int tid = threadIdx.x;
    xs[tid] = X[(size_t)n * D_DIM + tid];
    __syncthreads();
    double best = DBL_MAX; int bi = 0x7fffffff;
    for (int k = tid; k < K_DIM; k += 256) {
        double s0=0,s1=0,s2=0,s3=0;
#pragma unroll 4
        for (int d = 0; d < D_DIM; d += 4) {
            double f0=(double)xs[d+0]-(double)E[(size_t)(d+0)*K_DIM+k];
            double f1=(double)xs[d+1]-(double)E[(size_t)(d+1)*K_DIM+k];
            double f2=(double)xs[d+2]-(double)E[(size_t)(d+2)*K_DIM+k];
            double f3=(double)xs[d+3]-(double)E[(size_t)(d+3)*K_DIM+k];
            s0=fma(f0,f0,s0); s1=fma(f1,f1,s1); s2=fma(f2,f2,s2); s3=fma(f3,f3,s3);
        }
        double s=(s0+s1)+(s2+s3);
        if (s<best){best=s;bi=k;}
    }
    __shared__ double bv[256]; __shared__ int bix[256];
    bv[tid]=best; bix[tid]=bi;
    __syncthreads();
    if (tid==0) {
        double b=bv[0]; int ix=bix[0];
        for (int t=1;t<256;++t)
            if (bv[t]<b || (bv[t]==b && bix[t]<ix)) { b=bv[t]; ix=bix[t]; }
        idx[n]=ix;
    }
}

// ---------------------------------------------------------------------------
extern "C" void kernel_launch(void* const* d_in, const int* in_sizes, int n_in,
                              void* d_out, int out_size, void* d_ws, size_t ws_size,
                              hipStream_t stream) {
    const float* X = (const float*)d_in[0];
    const float* E = (const float*)d_in[1];
    float* out = (float*)d_out;
    char* ws = (char*)d_ws;

    // fast-path workspace layout
    const size_t o_nhen  = 0;
    const size_t o_pb    = 32768;
    const size_t o_ps    = o_pb  + (size_t)KSPLIT * N_ROWS * 4;
    const size_t o_pi    = o_ps  + (size_t)KSPLIT * N_ROWS * 4;
    const size_t o_idx   = o_pi  + (size_t)KSPLIT * N_ROWS * 4;
    const size_t o_gap2  = o_idx + (size_t)N_ROWS * 4;
    const size_t o_list  = o_gap2 + (size_t)N_ROWS * 4;
    const size_t o_count = o_list + (size_t)T2CAP * 4;
    const size_t o_t2b   = o_count + 256;
    const size_t o_t2s   = o_t2b + (size_t)16 * T2CAP * 4;
    const size_t o_t2i   = o_t2s + (size_t)16 * T2CAP * 4;
    const size_t o_x16   = o_t2i + (size_t)16 * T2CAP * 4;
    const size_t o_epack = o_x16 + (size_t)N_ROWS * D_DIM * 2;
    const size_t NEED    = o_epack + (size_t)D_DIM * K_DIM * 2;

    if (ws_size >= NEED) {
        float* nhen  = (float*)(ws + o_nhen);
        float* p_b   = (float*)(ws + o_pb);
        float* p_s   = (float*)(ws + o_ps);
        int*   p_i   = (int*)  (ws + o_pi);
        int*   idxf  = (int*)  (ws + o_idx);
        float* gap2  = (float*)(ws + o_gap2);
        int*   list  = (int*)  (ws + o_list);
        int*   count = (int*)  (ws + o_count);
        float* t2b   = (float*)(ws + o_t2b);
        float* t2s   = (float*)(ws + o_t2s);
        int*   t2i   = (int*)  (ws + o_t2i);
        f16*   X16   = (f16*)  (ws + o_x16);
        f16*   Epack = (f16*)  (ws + o_epack);

        convx_kernel<<<(N_ROWS * D_DIM / 8) / 256, 256, 0, stream>>>(X, X16);
        packe_kernel<<<(K_DIM / 16) * 8 * 64 / 256, 256, 0, stream>>>(E, Epack);
        nhen_kernel<<<K_DIM / 256, 256, 0, stream>>>(E, nhen);
        zero_count_kernel<<<1, 1, 0, stream>>>(count);
        pass1_kernel<<<(N_ROWS / 256) * KSPLIT, 256, 0, stream>>>(
            X16, Epack, nhen, p_b, p_s, p_i);
        merge_kernel<<<N_ROWS / 256, 256, 0, stream>>>(
            p_b, p_s, p_i, idxf, gap2, list, count);
        tier2_kernel<<<(T2CAP / 64) * 16, 256, 0, stream>>>(
            X, E, nhen, list, count, t2b, t2s, t2i);
        merge2_kernel<<<T2CAP / 256, 256, 0, stream>>>(
            t2b, t2s, t2i, list, count, idxf, gap2);
        tier3_kernel<<<N_ROWS, 256, 0, stream>>>(X, E, gap2, idxf);
        gather_kernel<<<N_ROWS, 256, 0, stream>>>(E, idxf, out);
    } else {
        float* enorm = (float*)ws;
        int*   idx   = (int*)(ws + 32768);
        float* gap   = (float*)(ws + 32768 + (size_t)N_ROWS * 4);
        fb_enorm_kernel<<<K_DIM / 256, 256, 0, stream>>>(E, enorm);
        fb_dist_kernel<<<N_ROWS / 64, 256, 0, stream>>>(X, E, enorm, idx, gap);
        fb_refine_kernel<<<N_ROWS, 256, 0, stream>>>(X, E, gap, idx);
        gather_kernel<<<N_ROWS, 256, 0, stream>>>(E, idx, out);
    }
}

// Round 4
// 427.040 us; speedup vs baseline: 6.1748x; 1.6098x over previous
//
#include <hip/hip_runtime.h>
#include <math.h>
#include <float.h>

#define N_ROWS 32768
#define D_DIM  256
#define K_DIM  8192

#define EPS1 0.40f   // tier-1 (f16) gap threshold, full-distance scale
#define EPS2 0.02f   // tier-2 (fp32) gap threshold
#define T2CAP 4096   // tier-2 row capacity
#define T3CAP 512    // tier-3 row capacity
#define NSPLIT3 16   // tier-3 K splits (512 cols each)

typedef _Float16 f16;
typedef _Float16 f16x8 __attribute__((ext_vector_type(8)));
typedef float f32x4 __attribute__((ext_vector_type(4)));

#define KSPLIT 4
#define COLS_PER_SPLIT (K_DIM / KSPLIT)     // 2048
#define CHUNK_COLS 32
#define NCHUNK (COLS_PER_SPLIT / CHUNK_COLS) // 64

// ---------------------------------------------------------------------------
// convert X fp32 -> f16, [N][D] row-major. 8 elems/thread.
// ---------------------------------------------------------------------------
__global__ void convx_kernel(const float* __restrict__ X, f16* __restrict__ X16) {
    const size_t i = ((size_t)blockIdx.x * 256 + threadIdx.x) * 8;
    float4 a = *reinterpret_cast<const float4*>(X + i);
    float4 b = *reinterpret_cast<const float4*>(X + i + 4);
    f16x8 o;
    o[0]=(f16)a.x; o[1]=(f16)a.y; o[2]=(f16)a.z; o[3]=(f16)a.w;
    o[4]=(f16)b.x; o[5]=(f16)b.y; o[6]=(f16)b.z; o[7]=(f16)b.w;
    *reinterpret_cast<f16x8*>(X16 + i) = o;
}

// ---------------------------------------------------------------------------
// pack E fp32 [D][K] -> Epack f16 in B-fragment-linear order.
// B-frag (16x16x32): lane l, elem j  <-  E[32t + (l>>4)*8 + j][16*tile + (l&15)]
// Epack[(tile*8 + t)*512 + l*8 + j]
// ---------------------------------------------------------------------------
__global__ void packe_kernel(const float* __restrict__ E, f16* __restrict__ Epack) {
    const int gid = blockIdx.x * 256 + threadIdx.x;  // 512*8*64 = 262144
    const int l    = gid & 63;
    const int t    = (gid >> 6) & 7;
    const int tile = gid >> 9;
    const int k  = 16 * tile + (l & 15);
    const int d0 = 32 * t + (l >> 4) * 8;
    f16x8 o;
#pragma unroll
    for (int j = 0; j < 8; ++j) o[j] = (f16)E[(size_t)(d0 + j) * K_DIM + k];
    *reinterpret_cast<f16x8*>(Epack + (size_t)gid * 8) = o;
}

// ---------------------------------------------------------------------------
// nhen[k] = -0.5 * sum_d E[d][k]^2   (fp32)
// ---------------------------------------------------------------------------
__global__ void nhen_kernel(const float* __restrict__ E, float* __restrict__ nhen) {
    const int k = blockIdx.x * 256 + threadIdx.x;
    float s = 0.0f;
#pragma unroll 8
    for (int d = 0; d < D_DIM; ++d) {
        float v = E[(size_t)d * K_DIM + k];
        s = fmaf(v, v, s);
    }
    nhen[k] = -0.5f * s;
}

// ---------------------------------------------------------------------------
// pass1: f16 MFMA fused GEMM + per-row top-2 argmax of u = x.e - 0.5||e||^2
// ---------------------------------------------------------------------------
__launch_bounds__(256, 2)
__global__ void pass1_kernel(const f16* __restrict__ X16,
                             const f16* __restrict__ Epack,
                             const float* __restrict__ nhen,
                             float* __restrict__ p_best,
                             float* __restrict__ p_sec,
                             int*   __restrict__ p_idx) {
    __shared__ f16 B_lds[2][8192];   // 2 x 16KB (32 cols x 256 d)

    const int tid = threadIdx.x;
    const int wv = tid >> 6;
    const int lane = tid & 63;
    const int l15 = lane & 15;
    const int l4  = lane >> 4;
    const int rg = blockIdx.x >> 2;
    const int ks = blockIdx.x & 3;
    const int rowW = rg * 256 + wv * 64;
    const int colBase = ks * COLS_PER_SPLIT;

    f16x8 A[4][8];
#pragma unroll
    for (int rt = 0; rt < 4; ++rt)
#pragma unroll
        for (int t = 0; t < 8; ++t)
            A[rt][t] = *reinterpret_cast<const f16x8*>(
                X16 + (size_t)(rowW + 16*rt + l15) * D_DIM + 32*t + l4*8);

    float best[16], sec[16];
    int bbase[16];
#pragma unroll
    for (int s = 0; s < 16; ++s) { best[s] = -INFINITY; sec[s] = -INFINITY; bbase[s] = 0; }

    const float4* src = reinterpret_cast<const float4*>(
        Epack + (size_t)(ks * 128) * 8 * 512);

    float4 sreg[4];
#pragma unroll
    for (int q = 0; q < 4; ++q) sreg[q] = src[q*256 + tid];
    {
        float4* bw = reinterpret_cast<float4*>(&B_lds[0][0]);
#pragma unroll
        for (int q = 0; q < 4; ++q) bw[q*256 + tid] = sreg[q];
    }

    for (int ci = 0; ci < NCHUNK; ++ci) {
        __syncthreads();
        if (ci + 1 < NCHUNK) {
#pragma unroll
            for (int q = 0; q < 4; ++q)
                sreg[q] = src[(size_t)(ci+1)*1024 + q*256 + tid];
        }
        const f16* bufc = &B_lds[ci & 1][0];
        const int c0 = colBase + ci * CHUNK_COLS;

#pragma unroll
        for (int ct = 0; ct < 2; ++ct) {
            const float nh = nhen[c0 + 16*ct + l15];
            const f32x4 nh4 = {nh, nh, nh, nh};
            f32x4 acc[4];
            {
                f16x8 B = *reinterpret_cast<const f16x8*>(bufc + (ct*8)*512 + lane*8);
#pragma unroll
                for (int rt = 0; rt < 4; ++rt)
                    acc[rt] = __builtin_amdgcn_mfma_f32_16x16x32_f16(A[rt][0], B, nh4, 0, 0, 0);
            }
#pragma unroll
            for (int t = 1; t < 8; ++t) {
                f16x8 B = *reinterpret_cast<const f16x8*>(bufc + (ct*8 + t)*512 + lane*8);
#pragma unroll
                for (int rt = 0; rt < 4; ++rt)
                    acc[rt] = __builtin_amdgcn_mfma_f32_16x16x32_f16(A[rt][t], B, acc[rt], 0, 0, 0);
            }
#pragma unroll
            for (int rt = 0; rt < 4; ++rt) {
#pragma unroll
                for (int r = 0; r < 4; ++r) {
                    const float v = acc[rt][r];
                    const int sl = rt*4 + r;
                    const bool gt = v > best[sl];
                    sec[sl]  = fmaxf(sec[sl], fminf(v, best[sl]));
                    best[sl] = gt ? v : best[sl];
                    bbase[sl] = gt ? (c0 + 16*ct) : bbase[sl];
                }
            }
        }

        if (ci + 1 < NCHUNK) {
            float4* bw = reinterpret_cast<float4*>(&B_lds[(ci+1) & 1][0]);
#pragma unroll
            for (int q = 0; q < 4; ++q) bw[q*256 + tid] = sreg[q];
        }
    }

#pragma unroll
    for (int s = 0; s < 16; ++s) {
        float b = best[s], sc = sec[s];
        int k = bbase[s] + l15;
#pragma unroll
        for (int off = 8; off >= 1; off >>= 1) {
            float ob = __shfl_xor(b, off, 16);
            float os = __shfl_xor(sc, off, 16);
            int   ok = __shfl_xor(k, off, 16);
            float sm = fmaxf(fmaxf(sc, os), fminf(b, ob));
            bool take = (ob > b) || (ob == b && ok < k);
            b = take ? ob : b;
            k = take ? ok : k;
            sc = sm;
        }
        if (l15 == 0) {
            const int row = rowW + 16*(s >> 2) + 4*l4 + (s & 3);
            p_best[ks * N_ROWS + row] = b;
            p_sec [ks * N_ROWS + row] = sc;
            p_idx [ks * N_ROWS + row] = k;
        }
    }
}

// ---------------------------------------------------------------------------
__global__ void zero_counts_kernel(int* count, int* count3) { *count = 0; *count3 = 0; }

// merge K-splits; flag rows with gap < EPS1 into compacted tier-2 list
__global__ void merge_kernel(const float* __restrict__ p_best,
                             const float* __restrict__ p_sec,
                             const int*   __restrict__ p_idx,
                             int* __restrict__ idxf,
                             int* __restrict__ list, int* __restrict__ count) {
    const int n = blockIdx.x * 256 + threadIdx.x;
    float b = p_best[n], sc = p_sec[n];
    int k = p_idx[n];
#pragma unroll
    for (int s = 1; s < KSPLIT; ++s) {
        float ob = p_best[s * N_ROWS + n];
        float os = p_sec [s * N_ROWS + n];
        int   ok = p_idx [s * N_ROWS + n];
        float sm = fmaxf(fmaxf(sc, os), fminf(b, ob));
        bool take = ob > b;            // equal -> keep earlier split (smaller k)
        b = take ? ob : b; k = take ? ok : k; sc = sm;
    }
    idxf[n] = k;
    if (2.0f * (b - sc) < EPS1) {
        int pos = atomicAdd(count, 1);
        if (pos < T2CAP) list[pos] = n;
    }
}

// ---------------------------------------------------------------------------
// tier-2: fp32 rescan of flagged rows. Block = (group of 64 rows) x (512-col
// split). Tracks top-2 max of u = dot + nhen.
// ---------------------------------------------------------------------------
__launch_bounds__(256, 2)
__global__ void tier2_kernel(const float* __restrict__ X,
                             const float* __restrict__ E,
                             const float* __restrict__ nhen,
                             const int* __restrict__ list,
                             const int* __restrict__ count,
                             float* __restrict__ t2b, float* __restrict__ t2s,
                             int* __restrict__ t2i) {
    const int g  = blockIdx.x >> 4;
    const int sp = blockIdx.x & 15;
    const int cnt = min(*count, T2CAP);
    if (g * 64 >= cnt) return;

    __shared__ float xT[D_DIM][64];
    __shared__ float es[64][64];
    const int tid = threadIdx.x;
    const int tx = tid & 15, ty = tid >> 4;

    {
        const int r = tid >> 2;
        const int slot = min(g * 64 + r, cnt - 1);
        const int row = list[slot];
        const int d0 = (tid & 3) * 64;
        const float* xp = X + (size_t)row * D_DIM + d0;
#pragma unroll
        for (int i = 0; i < 64; i += 4) {
            float4 v = *reinterpret_cast<const float4*>(xp + i);
            xT[d0+i+0][r] = v.x; xT[d0+i+1][r] = v.y;
            xT[d0+i+2][r] = v.z; xT[d0+i+3][r] = v.w;
        }
    }

    float best[4], sec[4]; int bidx[4];
#pragma unroll
    for (int i = 0; i < 4; ++i) { best[i] = -INFINITY; sec[i] = -INFINITY; bidx[i] = 0; }

    const int colBase = sp * 512;
    for (int kc = 0; kc < 512; kc += 64) {
        float acc[4][4];
#pragma unroll
        for (int i = 0; i < 4; ++i)
#pragma unroll
            for (int j = 0; j < 4; ++j) acc[i][j] = 0.0f;

        for (int dc = 0; dc < D_DIM; dc += 64) {
            __syncthreads();
#pragma unroll
            for (int dd = 0; dd < 64; dd += 16) {
                int d = dd + (tid >> 4);
                float4 v = *reinterpret_cast<const float4*>(
                    &E[(size_t)(dc + d) * K_DIM + colBase + kc + (tid & 15) * 4]);
                *reinterpret_cast<float4*>(&es[d][(tid & 15) * 4]) = v;
            }
            __syncthreads();
#pragma unroll 8
            for (int d = 0; d < 64; ++d) {
                float4 xv = *reinterpret_cast<const float4*>(&xT[dc + d][ty * 4]);
                float4 ev = *reinterpret_cast<const float4*>(&es[d][tx * 4]);
                float xr[4] = {xv.x, xv.y, xv.z, xv.w};
                float ec[4] = {ev.x, ev.y, ev.z, ev.w};
#pragma unroll
                for (int i = 0; i < 4; ++i)
#pragma unroll
                    for (int j = 0; j < 4; ++j)
                        acc[i][j] = fmaf(xr[i], ec[j], acc[i][j]);
            }
        }
        float4 nhv = *reinterpret_cast<const float4*>(&nhen[colBase + kc + tx * 4]);
        float nh[4] = {nhv.x, nhv.y, nhv.z, nhv.w};
#pragma unroll
        for (int j = 0; j < 4; ++j) {
            const int k = colBase + kc + tx * 4 + j;
#pragma unroll
            for (int i = 0; i < 4; ++i) {
                float u = nh[j] + acc[i][j];
                bool gt = u > best[i];
                sec[i]  = fmaxf(sec[i], fminf(u, best[i]));
                best[i] = gt ? u : best[i];
                bidx[i] = gt ? k : bidx[i];
            }
        }
    }

#pragma unroll
    for (int off = 8; off >= 1; off >>= 1) {
#pragma unroll
        for (int i = 0; i < 4; ++i) {
            float ob = __shfl_xor(best[i], off, 16);
            float os = __shfl_xor(sec[i], off, 16);
            int   ok = __shfl_xor(bidx[i], off, 16);
            float sm = fmaxf(fmaxf(sec[i], os), fminf(best[i], ob));
            bool take = (ob > best[i]) || (ob == best[i] && ok < bidx[i]);
            best[i] = take ? ob : best[i];
            bidx[i] = take ? ok : bidx[i];
            sec[i] = sm;
        }
    }
    if (tx == 0) {
#pragma unroll
        for (int i = 0; i < 4; ++i) {
            const int slot = g * 64 + ty * 4 + i;
            if (slot < cnt) {
                t2b[sp * T2CAP + slot] = best[i];
                t2s[sp * T2CAP + slot] = sec[i];
                t2i[sp * T2CAP + slot] = bidx[i];
            }
        }
    }
}

// merge tier-2 splits; flag knife-edge rows into compacted tier-3 list
__global__ void merge2_kernel(const float* __restrict__ t2b,
                              const float* __restrict__ t2s,
                              const int*   __restrict__ t2i,
                              const int* __restrict__ list,
                              const int* __restrict__ count,
                              int* __restrict__ idxf,
                              int* __restrict__ list3, int* __restrict__ count3) {
    const int slot = blockIdx.x * 256 + threadIdx.x;
    const int cnt = min(*count, T2CAP);
    if (slot >= cnt) return;
    float b = t2b[slot], sc = t2s[slot];
    int k = t2i[slot];
#pragma unroll
    for (int sp = 1; sp < 16; ++sp) {
        float ob = t2b[sp * T2CAP + slot];
        float os = t2s[sp * T2CAP + slot];
        int   ok = t2i[sp * T2CAP + slot];
        float sm = fmaxf(fmaxf(sc, os), fminf(b, ob));
        bool take = ob > b;
        b = take ? ob : b; k = take ? ok : k; sc = sm;
    }
    const int n = list[slot];
    idxf[n] = k;
    if (2.0f * (b - sc) < EPS2) {
        int pos = atomicAdd(count3, 1);
        if (pos < T3CAP) list3[pos] = n;
    }
}

// ---------------------------------------------------------------------------
// tier-3: fp64 exact rescan, K split 16 ways across blocks. Block =
// (slot, split of 512 cols); partial (best,idx) per split, merged by merge3.
// ---------------------------------------------------------------------------
__launch_bounds__(256)
__global__ void tier3_kernel(const float* __restrict__ X,
                             const float* __restrict__ E,
                             const int* __restrict__ list3,
                             const int* __restrict__ count3,
                             double* __restrict__ t3b, int* __restrict__ t3i) {
    const int slot = blockIdx.x >> 4;
    const int sp   = blockIdx.x & 15;
    const int cnt = min(*count3, T3CAP);
    if (slot >= cnt) return;
    const int n = list3[slot];

    __shared__ float xs[D_DIM];
    const int tid = threadIdx.x;
    xs[tid] = X[(size_t)n * D_DIM + tid];
    __syncthreads();

    const int colBase = sp * 512;
    double best = DBL_MAX;
    int bi = 0x7fffffff;
#pragma unroll
    for (int kk = 0; kk < 512; kk += 256) {
        const int k = colBase + kk + tid;
        double s0 = 0.0, s1 = 0.0, s2 = 0.0, s3 = 0.0;
#pragma unroll 4
        for (int d = 0; d < D_DIM; d += 4) {
            double f0 = (double)xs[d+0] - (double)E[(size_t)(d+0) * K_DIM + k];
            double f1 = (double)xs[d+1] - (double)E[(size_t)(d+1) * K_DIM + k];
            double f2 = (double)xs[d+2] - (double)E[(size_t)(d+2) * K_DIM + k];
            double f3 = (double)xs[d+3] - (double)E[(size_t)(d+3) * K_DIM + k];
            s0 = fma(f0, f0, s0); s1 = fma(f1, f1, s1);
            s2 = fma(f2, f2, s2); s3 = fma(f3, f3, s3);
        }
        double s = (s0 + s1) + (s2 + s3);
        if (s < best) { best = s; bi = k; }   // k ascending per thread
    }

    __shared__ double bv[256];
    __shared__ int bix[256];
    bv[tid] = best; bix[tid] = bi;
    __syncthreads();
    if (tid == 0) {
        double b = bv[0]; int ix = bix[0];
        for (int t = 1; t < 256; ++t)
            if (bv[t] < b || (bv[t] == b && bix[t] < ix)) { b = bv[t]; ix = bix[t]; }
        t3b[sp * T3CAP + slot] = b;
        t3i[sp * T3CAP + slot] = ix;
    }
}

__global__ void merge3_kernel(const double* __restrict__ t3b,
                              const int* __restrict__ t3i,
                              const int* __restrict__ list3,
                              const int* __restrict__ count3,
                              int* __restrict__ idxf) {
    const int slot = blockIdx.x * 256 + threadIdx.x;
    const int cnt = min(*count3, T3CAP);
    if (slot >= cnt) return;
    double b = t3b[slot];
    int k = t3i[slot];
#pragma unroll
    for (int sp = 1; sp < NSPLIT3; ++sp) {
        double ob = t3b[sp * T3CAP + slot];
        int   ok = t3i[sp * T3CAP + slot];
        if (ob < b || (ob == b && ok < k)) { b = ob; k = ok; }
    }
    idxf[list3[slot]] = k;
}

// ---------------------------------------------------------------------------
__global__ void gather_kernel(const float* __restrict__ E,
                              const int* __restrict__ idx,
                              float* __restrict__ out) {
    const int n = blockIdx.x;
    const int d = threadIdx.x;
    const int k = idx[n];
    out[(size_t)n * D_DIM + d] = E[(size_t)d * K_DIM + k];
}

// ======================= fallback path (proven round-2) =====================
__global__ void fb_enorm_kernel(const float* __restrict__ E, float* __restrict__ enorm) {
    int k = blockIdx.x * 256 + threadIdx.x;
    float s = 0.0f;
#pragma unroll 8
    for (int d = 0; d < D_DIM; ++d) { float v = E[(size_t)d * K_DIM + k]; s = fmaf(v, v, s); }
    enorm[k] = s;
}

__launch_bounds__(256, 2)
__global__ void fb_dist_kernel(const float* __restrict__ X, const float* __restrict__ E,
                               const float* __restrict__ enorm,
                               int* __restrict__ idx_out, float* __restrict__ gap_out) {
    __shared__ float xT[D_DIM][64];
    __shared__ float es[64][64];
    const int tid = threadIdx.x;
    const int tx = tid & 15, ty = tid >> 4;
    const int rowBase = blockIdx.x * 64;
    {
        const int r = tid >> 2;
        const int d0 = (tid & 3) * 64;
        const float* xp = X + (size_t)(rowBase + r) * D_DIM + d0;
#pragma unroll
        for (int i = 0; i < 64; i += 4) {
            float4 v = *reinterpret_cast<const float4*>(xp + i);
            xT[d0+i+0][r]=v.x; xT[d0+i+1][r]=v.y; xT[d0+i+2][r]=v.z; xT[d0+i+3][r]=v.w;
        }
    }
    float bestVal[4], secVal[4]; int bestIdx[4];
#pragma unroll
    for (int i = 0; i < 4; ++i) { bestVal[i]=INFINITY; secVal[i]=INFINITY; bestIdx[i]=0; }
    for (int kc = 0; kc < K_DIM; kc += 64) {
        float acc[4][4];
#pragma unroll
        for (int i=0;i<4;++i)
#pragma unroll
            for (int j=0;j<4;++j) acc[i][j]=0.f;
        for (int dc = 0; dc < D_DIM; dc += 64) {
            __syncthreads();
#pragma unroll
            for (int dd = 0; dd < 64; dd += 16) {
                int d = dd + (tid >> 4);
                float4 v = *reinterpret_cast<const float4*>(
                    &E[(size_t)(dc+d)*K_DIM + kc + (tid&15)*4]);
                *reinterpret_cast<float4*>(&es[d][(tid&15)*4]) = v;
            }
            __syncthreads();
#pragma unroll 8
            for (int d = 0; d < 64; ++d) {
                float4 xv = *reinterpret_cast<const float4*>(&xT[dc+d][ty*4]);
                float4 ev = *reinterpret_cast<const float4*>(&es[d][tx*4]);
                float xr[4]={xv.x,xv.y,xv.z,xv.w}, ec[4]={ev.x,ev.y,ev.z,ev.w};
#pragma unroll
                for (int i=0;i<4;++i)
#pragma unroll
                    for (int j=0;j<4;++j) acc[i][j]=fmaf(xr[i],ec[j],acc[i][j]);
            }
        }
        float4 env = *reinterpret_cast<const float4*>(&enorm[kc + tx*4]);
        float en[4]={env.x,env.y,env.z,env.w};
#pragma unroll
        for (int j=0;j<4;++j) {
            int k = kc + tx*4 + j;
#pragma unroll
            for (int i=0;i<4;++i) {
                float s = fmaf(-2.0f, acc[i][j], en[j]);
                if (s < bestVal[i]) { secVal[i]=bestVal[i]; bestVal[i]=s; bestIdx[i]=k; }
                else if (s < secVal[i]) secVal[i]=s;
            }
        }
    }
#pragma unroll
    for (int off=8; off>=1; off>>=1) {
#pragma unroll
        for (int i=0;i<4;++i) {
            float oB=__shfl_xor(bestVal[i],off,16);
            int oI=__shfl_xor(bestIdx[i],off,16);
            float oS=__shfl_xor(secVal[i],off,16);
            float ms=fminf(fminf(secVal[i],oS),fmaxf(bestVal[i],oB));
            if (oB<bestVal[i] || (oB==bestVal[i] && oI<bestIdx[i])) { bestVal[i]=oB; bestIdx[i]=oI; }
            secVal[i]=ms;
        }
    }
    if (tx==0) {
#pragma unroll
        for (int i=0;i<4;++i) {
            idx_out[rowBase + ty*4 + i] = bestIdx[i];
            gap_out[rowBase + ty*4 + i] = secVal[i]-bestVal[i];
        }
    }
}

__launch_bounds__(256)
__global__ void fb_refine_kernel(const float* __restrict__ X, const float* __restrict__ E,
                                 const float* __restrict__ gap, int* __restrict__ idx) {
    const int n = blockIdx.x;
    if (gap[n] >= 0.0625f) return;
    __shared__ float xs[D_DIM];
    const int tid = threadIdx.x;
    xs[tid] = X[(size_t)n * D_DIM + tid];
    __syncthreads();
    double best = DBL_MAX; int bi = 0x7fffffff;
    for (int k = tid; k < K_DIM; k += 256) {
        double s0=0,s1=0,s2=0,s3=0;
#pragma unroll 4
        for (int d = 0; d < D_DIM; d += 4) {
            double f0=(double)xs[d+0]-(double)E[(size_t)(d+0)*K_DIM+k];
            double f1=(double)xs[d+1]-(double)E[(size_t)(d+1)*K_DIM+k];
            double f2=(double)xs[d+2]-(double)E[(size_t)(d+2)*K_DIM+k];
            double f3=(double)xs[d+3]-(double)E[(size_t)(d+3)*K_DIM+k];
            s0=fma(f0,f0,s0); s1=fma(f1,f1,s1); s2=fma(f2,f2,s2); s3=fma(f3,f3,s3);
        }
        double s=(s0+s1)+(s2+s3);
        if (s<best){best=s;bi=k;}
    }
    __shared__ double bv[256]; __shared__ int bix[256];
    bv[tid]=best; bix[tid]=bi;
    __syncthreads();
    if (tid==0) {
        double b=bv[0]; int ix=bix[0];
        for (int t=1;t<256;++t)
            if (bv[t]<b || (bv[t]==b && bix[t]<ix)) { b=bv[t]; ix=bix[t]; }
        idx[n]=ix;
    }
}

// ---------------------------------------------------------------------------
extern "C" void kernel_launch(void* const* d_in, const int* in_sizes, int n_in,
                              void* d_out, int out_size, void* d_ws, size_t ws_size,
                              hipStream_t stream) {
    const float* X = (const float*)d_in[0];
    const float* E = (const float*)d_in[1];
    float* out = (float*)d_out;
    char* ws = (char*)d_ws;

    // fast-path workspace layout (all offsets 256B-aligned)
    const size_t o_nhen  = 0;                                       // K*4 = 32768
    const size_t o_pb    = 32768;
    const size_t o_ps    = o_pb  + (size_t)KSPLIT * N_ROWS * 4;
    const size_t o_pi    = o_ps  + (size_t)KSPLIT * N_ROWS * 4;
    const size_t o_idx   = o_pi  + (size_t)KSPLIT * N_ROWS * 4;
    const size_t o_list  = o_idx + (size_t)N_ROWS * 4;
    const size_t o_count = o_list + (size_t)T2CAP * 4;              // count @+0, count3 @+4
    const size_t o_t2b   = o_count + 256;
    const size_t o_t2s   = o_t2b + (size_t)16 * T2CAP * 4;
    const size_t o_t2i   = o_t2s + (size_t)16 * T2CAP * 4;
    const size_t o_list3 = o_t2i + (size_t)16 * T2CAP * 4;
    const size_t o_t3b   = o_list3 + (size_t)T3CAP * 4;             // 8B-aligned
    const size_t o_t3i   = o_t3b + (size_t)NSPLIT3 * T3CAP * 8;
    const size_t o_x16   = o_t3i + (size_t)NSPLIT3 * T3CAP * 4;
    const size_t o_epack = o_x16 + (size_t)N_ROWS * D_DIM * 2;
    const size_t NEED    = o_epack + (size_t)D_DIM * K_DIM * 2;

    if (ws_size >= NEED) {
        float*  nhen  = (float*) (ws + o_nhen);
        float*  p_b   = (float*) (ws + o_pb);
        float*  p_s   = (float*) (ws + o_ps);
        int*    p_i   = (int*)   (ws + o_pi);
        int*    idxf  = (int*)   (ws + o_idx);
        int*    list  = (int*)   (ws + o_list);
        int*    count = (int*)   (ws + o_count);
        int*    count3= (int*)   (ws + o_count + 4);
        float*  t2b   = (float*) (ws + o_t2b);
        float*  t2s   = (float*) (ws + o_t2s);
        int*    t2i   = (int*)   (ws + o_t2i);
        int*    list3 = (int*)   (ws + o_list3);
        double* t3b   = (double*)(ws + o_t3b);
        int*    t3i   = (int*)   (ws + o_t3i);
        f16*    X16   = (f16*)   (ws + o_x16);
        f16*    Epack = (f16*)   (ws + o_epack);

        convx_kernel<<<(N_ROWS * D_DIM / 8) / 256, 256, 0, stream>>>(X, X16);
        packe_kernel<<<(K_DIM / 16) * 8 * 64 / 256, 256, 0, stream>>>(E, Epack);
        nhen_kernel<<<K_DIM / 256, 256, 0, stream>>>(E, nhen);
        zero_counts_kernel<<<1, 1, 0, stream>>>(count, count3);
        pass1_kernel<<<(N_ROWS / 256) * KSPLIT, 256, 0, stream>>>(
            X16, Epack, nhen, p_b, p_s, p_i);
        merge_kernel<<<N_ROWS / 256, 256, 0, stream>>>(
            p_b, p_s, p_i, idxf, list, count);
        tier2_kernel<<<(T2CAP / 64) * 16, 256, 0, stream>>>(
            X, E, nhen, list, count, t2b, t2s, t2i);
        merge2_kernel<<<T2CAP / 256, 256, 0, stream>>>(
            t2b, t2s, t2i, list, count, idxf, list3, count3);
        tier3_kernel<<<T3CAP * NSPLIT3, 256, 0, stream>>>(
            X, E, list3, count3, t3b, t3i);
        merge3_kernel<<<T3CAP / 256, 256, 0, stream>>>(
            t3b, t3i, list3, count3, idxf);
        gather_kernel<<<N_ROWS, 256, 0, stream>>>(E, idxf, out);
    } else {
        float* enorm = (float*)ws;
        int*   idx   = (int*)(ws + 32768);
        float* gap   = (float*)(ws + 32768 + (size_t)N_ROWS * 4);
        fb_enorm_kernel<<<K_DIM / 256, 256, 0, stream>>>(E, enorm);
        fb_dist_kernel<<<N_ROWS / 64, 256, 0, stream>>>(X, E, enorm, idx, gap);
        fb_refine_kernel<<<N_ROWS, 256, 0, stream>>>(X, E, gap, idx);
        gather_kernel<<<N_ROWS, 256, 0, stream>>>(E, idx, out);
    }
}

// Round 6
// 365.313 us; speedup vs baseline: 7.2181x; 1.1690x over previous
//
#include <hip/hip_runtime.h>
#include <math.h>
#include <float.h>

#define N_ROWS 32768
#define D_DIM  256
#define K_DIM  8192

#define EPS1 0.40f   // tier-1 (f16) gap threshold, full-distance scale
#define EPS2 0.02f   // tier-2 (fp32) gap threshold
#define T2CAP 4096   // tier-2 row capacity
#define T3CAP 512    // tier-3 row capacity
#define NSPLIT3 16   // tier-3 K splits (512 cols each)

typedef _Float16 f16;
typedef _Float16 f16x8 __attribute__((ext_vector_type(8)));
typedef float f32x4 __attribute__((ext_vector_type(4)));

#define KSPLIT 8
#define COLS_PER_SPLIT (K_DIM / KSPLIT)     // 1024
#define CHUNK_COLS 32
#define NCHUNK (COLS_PER_SPLIT / CHUNK_COLS) // 32

// ---------------------------------------------------------------------------
// convert X fp32 -> f16, [N][D] row-major. 8 elems/thread.
// ---------------------------------------------------------------------------
__global__ void convx_kernel(const float* __restrict__ X, f16* __restrict__ X16) {
    const size_t i = ((size_t)blockIdx.x * 256 + threadIdx.x) * 8;
    float4 a = *reinterpret_cast<const float4*>(X + i);
    float4 b = *reinterpret_cast<const float4*>(X + i + 4);
    f16x8 o;
    o[0]=(f16)a.x; o[1]=(f16)a.y; o[2]=(f16)a.z; o[3]=(f16)a.w;
    o[4]=(f16)b.x; o[5]=(f16)b.y; o[6]=(f16)b.z; o[7]=(f16)b.w;
    *reinterpret_cast<f16x8*>(X16 + i) = o;
}

// ---------------------------------------------------------------------------
// pack E fp32 [D][K] -> Epack f16 in B-fragment-linear order.
// B-frag (16x16x32): lane l, elem j  <-  E[32t + (l>>4)*8 + j][16*tile + (l&15)]
// Epack[(tile*8 + t)*512 + l*8 + j]   (one tile = 16 cols = 4096 f16)
// ---------------------------------------------------------------------------
__global__ void packe_kernel(const float* __restrict__ E, f16* __restrict__ Epack) {
    const int gid = blockIdx.x * 256 + threadIdx.x;  // 512*8*64 = 262144
    const int l    = gid & 63;
    const int t    = (gid >> 6) & 7;
    const int tile = gid >> 9;
    const int k  = 16 * tile + (l & 15);
    const int d0 = 32 * t + (l >> 4) * 8;
    f16x8 o;
#pragma unroll
    for (int j = 0; j < 8; ++j) o[j] = (f16)E[(size_t)(d0 + j) * K_DIM + k];
    *reinterpret_cast<f16x8*>(Epack + (size_t)gid * 8) = o;
}

// ---------------------------------------------------------------------------
// nhen[k] = -0.5 * sum_d E[d][k]^2   (fp32)
// ---------------------------------------------------------------------------
__global__ void nhen_kernel(const float* __restrict__ E, float* __restrict__ nhen) {
    const int k = blockIdx.x * 256 + threadIdx.x;
    float s = 0.0f;
#pragma unroll 8
    for (int d = 0; d < D_DIM; ++d) {
        float v = E[(size_t)d * K_DIM + k];
        s = fmaf(v, v, s);
    }
    nhen[k] = -0.5f * s;
}

// ---------------------------------------------------------------------------
// tiled transpose: ET[k][d] = E[d][k]  (for coalesced gather)
// ---------------------------------------------------------------------------
__global__ void transpose_kernel(const float* __restrict__ E, float* __restrict__ ET) {
    __shared__ float t[64][65];
    const int bk = blockIdx.x & (K_DIM / 64 - 1);   // 128 k-tiles
    const int bd = blockIdx.x >> 7;                 // 4 d-tiles
    const int c  = threadIdx.x & 63;
    const int r0 = (threadIdx.x >> 6) * 16;
    const int d0 = bd * 64, k0 = bk * 64;
#pragma unroll
    for (int i = 0; i < 16; ++i)
        t[r0 + i][c] = E[(size_t)(d0 + r0 + i) * K_DIM + k0 + c];
    __syncthreads();
#pragma unroll
    for (int i = 0; i < 16; ++i)
        ET[(size_t)(k0 + r0 + i) * D_DIM + d0 + c] = t[c][r0 + i];
}

// ---------------------------------------------------------------------------
// pass1: f16 MFMA fused GEMM + per-row top-2 argmax of u = x.e - 0.5||e||^2
// KSPLIT=8 -> 1024 blocks = 4 blocks/CU (VGPR 128, LDS 32KB both allow it).
// ---------------------------------------------------------------------------
__launch_bounds__(256, 2)
__global__ void pass1_kernel(const f16* __restrict__ X16,
                             const f16* __restrict__ Epack,
                             const float* __restrict__ nhen,
                             float* __restrict__ p_best,
                             float* __restrict__ p_sec,
                             int*   __restrict__ p_idx) {
    __shared__ f16 B_lds[2][8192];   // 2 x 16KB (32 cols x 256 d)

    const int tid = threadIdx.x;
    const int wv = tid >> 6;
    const int lane = tid & 63;
    const int l15 = lane & 15;
    const int l4  = lane >> 4;
    const int rg = blockIdx.x >> 3;
    const int ks = blockIdx.x & 7;
    const int rowW = rg * 256 + wv * 64;
    const int colBase = ks * COLS_PER_SPLIT;

    f16x8 A[4][8];
#pragma unroll
    for (int rt = 0; rt < 4; ++rt)
#pragma unroll
        for (int t = 0; t < 8; ++t)
            A[rt][t] = *reinterpret_cast<const f16x8*>(
                X16 + (size_t)(rowW + 16*rt + l15) * D_DIM + 32*t + l4*8);

    float best[16], sec[16];
    int bbase[16];
#pragma unroll
    for (int s = 0; s < 16; ++s) { best[s] = -INFINITY; sec[s] = -INFINITY; bbase[s] = 0; }

    // chunk source: tile index = colBase/16, each tile = 8*512 f16
    // -> f16 offset = (colBase/16)*4096 = colBase*256
    const float4* src = reinterpret_cast<const float4*>(
        Epack + (size_t)colBase * 256);

    float4 sreg[4];
#pragma unroll
    for (int q = 0; q < 4; ++q) sreg[q] = src[q*256 + tid];
    {
        float4* bw = reinterpret_cast<float4*>(&B_lds[0][0]);
#pragma unroll
        for (int q = 0; q < 4; ++q) bw[q*256 + tid] = sreg[q];
    }

    for (int ci = 0; ci < NCHUNK; ++ci) {
        __syncthreads();
        if (ci + 1 < NCHUNK) {
#pragma unroll
            for (int q = 0; q < 4; ++q)
                sreg[q] = src[(size_t)(ci+1)*1024 + q*256 + tid];
        }
        const f16* bufc = &B_lds[ci & 1][0];
        const int c0 = colBase + ci * CHUNK_COLS;

#pragma unroll
        for (int ct = 0; ct < 2; ++ct) {
            const float nh = nhen[c0 + 16*ct + l15];
            const f32x4 nh4 = {nh, nh, nh, nh};
            f32x4 acc[4];
            {
                f16x8 B = *reinterpret_cast<const f16x8*>(bufc + (ct*8)*512 + lane*8);
#pragma unroll
                for (int rt = 0; rt < 4; ++rt)
                    acc[rt] = __builtin_amdgcn_mfma_f32_16x16x32_f16(A[rt][0], B, nh4, 0, 0, 0);
            }
#pragma unroll
            for (int t = 1; t < 8; ++t) {
                f16x8 B = *reinterpret_cast<const f16x8*>(bufc + (ct*8 + t)*512 + lane*8);
#pragma unroll
                for (int rt = 0; rt < 4; ++rt)
                    acc[rt] = __builtin_amdgcn_mfma_f32_16x16x32_f16(A[rt][t], B, acc[rt], 0, 0, 0);
            }
            // top-2 tracking, 4 VALU/elem: med3 + cmp + 2 sel.
            // sec' = median(v, best_old, sec_old) is exactly the runner-up update
            // (invariant best >= sec holds from the -INF init).
#pragma unroll
            for (int rt = 0; rt < 4; ++rt) {
#pragma unroll
                for (int r = 0; r < 4; ++r) {
                    const float v = acc[rt][r];
                    const int sl = rt*4 + r;
                    sec[sl] = __builtin_amdgcn_fmed3f(v, best[sl], sec[sl]);
                    const bool gt = v > best[sl];
                    best[sl] = gt ? v : best[sl];
                    bbase[sl] = gt ? (c0 + 16*ct) : bbase[sl];
                }
            }
        }

        if (ci + 1 < NCHUNK) {
            float4* bw = reinterpret_cast<float4*>(&B_lds[(ci+1) & 1][0]);
#pragma unroll
            for (int q = 0; q < 4; ++q) bw[q*256 + tid] = sreg[q];
        }
    }

#pragma unroll
    for (int s = 0; s < 16; ++s) {
        float b = best[s], sc = sec[s];
        int k = bbase[s] + l15;
#pragma unroll
        for (int off = 8; off >= 1; off >>= 1) {
            float ob = __shfl_xor(b, off, 16);
            float os = __shfl_xor(sc, off, 16);
            int   ok = __shfl_xor(k, off, 16);
            float sm = fmaxf(fmaxf(sc, os), fminf(b, ob));
            bool take = (ob > b) || (ob == b && ok < k);
            b = take ? ob : b;
            k = take ? ok : k;
            sc = sm;
        }
        if (l15 == 0) {
            const int row = rowW + 16*(s >> 2) + 4*l4 + (s & 3);
            p_best[ks * N_ROWS + row] = b;
            p_sec [ks * N_ROWS + row] = sc;
            p_idx [ks * N_ROWS + row] = k;
        }
    }
}

// ---------------------------------------------------------------------------
__global__ void zero_counts_kernel(int* count, int* count3) { *count = 0; *count3 = 0; }

// merge K-splits; flag rows with gap < EPS1 into compacted tier-2 list
__global__ void merge_kernel(const float* __restrict__ p_best,
                             const float* __restrict__ p_sec,
                             const int*   __restrict__ p_idx,
                             int* __restrict__ idxf,
                             int* __restrict__ list, int* __restrict__ count) {
    const int n = blockIdx.x * 256 + threadIdx.x;
    float b = p_best[n], sc = p_sec[n];
    int k = p_idx[n];
#pragma unroll
    for (int s = 1; s < KSPLIT; ++s) {
        float ob = p_best[s * N_ROWS + n];
        float os = p_sec [s * N_ROWS + n];
        int   ok = p_idx [s * N_ROWS + n];
        float sm = fmaxf(fmaxf(sc, os), fminf(b, ob));
        bool take = ob > b;            // equal -> keep earlier split (smaller k)
        b = take ? ob : b; k = take ? ok : k; sc = sm;
    }
    idxf[n] = k;
    if (2.0f * (b - sc) < EPS1) {
        int pos = atomicAdd(count, 1);
        if (pos < T2CAP) list[pos] = n;
    }
}

// ---------------------------------------------------------------------------
// tier-2: fp32 rescan of flagged rows. Block = (group of 64 rows) x (512-col
// split). Tracks top-2 max of u = dot + nhen.
// ---------------------------------------------------------------------------
__launch_bounds__(256, 2)
__global__ void tier2_kernel(const float* __restrict__ X,
                             const float* __restrict__ E,
                             const float* __restrict__ nhen,
                             const int* __restrict__ list,
                             const int* __restrict__ count,
                             float* __restrict__ t2b, float* __restrict__ t2s,
                             int* __restrict__ t2i) {
    const int g  = blockIdx.x >> 4;
    const int sp = blockIdx.x & 15;
    const int cnt = min(*count, T2CAP);
    if (g * 64 >= cnt) return;

    __shared__ float xT[D_DIM][64];
    __shared__ float es[64][64];
    const int tid = threadIdx.x;
    const int tx = tid & 15, ty = tid >> 4;

    {
        const int r = tid >> 2;
        const int slot = min(g * 64 + r, cnt - 1);
        const int row = list[slot];
        const int d0 = (tid & 3) * 64;
        const float* xp = X + (size_t)row * D_DIM + d0;
#pragma unroll
        for (int i = 0; i < 64; i += 4) {
            float4 v = *reinterpret_cast<const float4*>(xp + i);
            xT[d0+i+0][r] = v.x; xT[d0+i+1][r] = v.y;
            xT[d0+i+2][r] = v.z; xT[d0+i+3][r] = v.w;
        }
    }

    float best[4], sec[4]; int bidx[4];
#pragma unroll
    for (int i = 0; i < 4; ++i) { best[i] = -INFINITY; sec[i] = -INFINITY; bidx[i] = 0; }

    const int colBase = sp * 512;
    for (int kc = 0; kc < 512; kc += 64) {
        float acc[4][4];
#pragma unroll
        for (int i = 0; i < 4; ++i)
#pragma unroll
            for (int j = 0; j < 4; ++j) acc[i][j] = 0.0f;

        for (int dc = 0; dc < D_DIM; dc += 64) {
            __syncthreads();
#pragma unroll
            for (int dd = 0; dd < 64; dd += 16) {
                int d = dd + (tid >> 4);
                float4 v = *reinterpret_cast<const float4*>(
                    &E[(size_t)(dc + d) * K_DIM + colBase + kc + (tid & 15) * 4]);
                *reinterpret_cast<float4*>(&es[d][(tid & 15) * 4]) = v;
            }
            __syncthreads();
#pragma unroll 8
            for (int d = 0; d < 64; ++d) {
                float4 xv = *reinterpret_cast<const float4*>(&xT[dc + d][ty * 4]);
                float4 ev = *reinterpret_cast<const float4*>(&es[d][tx * 4]);
                float xr[4] = {xv.x, xv.y, xv.z, xv.w};
                float ec[4] = {ev.x, ev.y, ev.z, ev.w};
#pragma unroll
                for (int i = 0; i < 4; ++i)
#pragma unroll
                    for (int j = 0; j < 4; ++j)
                        acc[i][j] = fmaf(xr[i], ec[j], acc[i][j]);
            }
        }
        float4 nhv = *reinterpret_cast<const float4*>(&nhen[colBase + kc + tx * 4]);
        float nh[4] = {nhv.x, nhv.y, nhv.z, nhv.w};
#pragma unroll
        for (int j = 0; j < 4; ++j) {
            const int k = colBase + kc + tx * 4 + j;
#pragma unroll
            for (int i = 0; i < 4; ++i) {
                float u = nh[j] + acc[i][j];
                bool gt = u > best[i];
                sec[i]  = fmaxf(sec[i], fminf(u, best[i]));
                best[i] = gt ? u : best[i];
                bidx[i] = gt ? k : bidx[i];
            }
        }
    }

#pragma unroll
    for (int off = 8; off >= 1; off >>= 1) {
#pragma unroll
        for (int i = 0; i < 4; ++i) {
            float ob = __shfl_xor(best[i], off, 16);
            float os = __shfl_xor(sec[i], off, 16);
            int   ok = __shfl_xor(bidx[i], off, 16);
            float sm = fmaxf(fmaxf(sec[i], os), fminf(best[i], ob));
            bool take = (ob > best[i]) || (ob == best[i] && ok < bidx[i]);
            best[i] = take ? ob : best[i];
            bidx[i] = take ? ok : bidx[i];
            sec[i] = sm;
        }
    }
    if (tx == 0) {
#pragma unroll
        for (int i = 0; i < 4; ++i) {
            const int slot = g * 64 + ty * 4 + i;
            if (slot < cnt) {
                t2b[sp * T2CAP + slot] = best[i];
                t2s[sp * T2CAP + slot] = sec[i];
                t2i[sp * T2CAP + slot] = bidx[i];
            }
        }
    }
}

// merge tier-2 splits; flag knife-edge rows into compacted tier-3 list
__global__ void merge2_kernel(const float* __restrict__ t2b,
                              const float* __restrict__ t2s,
                              const int*   __restrict__ t2i,
                              const int* __restrict__ list,
                              const int* __restrict__ count,
                              int* __restrict__ idxf,
                              int* __restrict__ list3, int* __restrict__ count3) {
    const int slot = blockIdx.x * 256 + threadIdx.x;
    const int cnt = min(*count, T2CAP);
    if (slot >= cnt) return;
    float b = t2b[slot], sc = t2s[slot];
    int k = t2i[slot];
#pragma unroll
    for (int sp = 1; sp < 16; ++sp) {
        float ob = t2b[sp * T2CAP + slot];
        float os = t2s[sp * T2CAP + slot];
        int   ok = t2i[sp * T2CAP + slot];
        float sm = fmaxf(fmaxf(sc, os), fminf(b, ob));
        bool take = ob > b;
        b = take ? ob : b; k = take ? ok : k; sc = sm;
    }
    const int n = list[slot];
    idxf[n] = k;
    if (2.0f * (b - sc) < EPS2) {
        int pos = atomicAdd(count3, 1);
        if (pos < T3CAP) list3[pos] = n;
    }
}

// ---------------------------------------------------------------------------
// tier-3: fp64 exact rescan, K split 16 ways across blocks.
// ---------------------------------------------------------------------------
__launch_bounds__(256)
__global__ void tier3_kernel(const float* __restrict__ X,
                             const float* __restrict__ E,
                             const int* __restrict__ list3,
                             const int* __restrict__ count3,
                             double* __restrict__ t3b, int* __restrict__ t3i) {
    const int slot = blockIdx.x >> 4;
    const int sp   = blockIdx.x & 15;
    const int cnt = min(*count3, T3CAP);
    if (slot >= cnt) return;
    const int n = list3[slot];

    __shared__ float xs[D_DIM];
    const int tid = threadIdx.x;
    xs[tid] = X[(size_t)n * D_DIM + tid];
    __syncthreads();

    const int colBase = sp * 512;
    double best = DBL_MAX;
    int bi = 0x7fffffff;
#pragma unroll
    for (int kk = 0; kk < 512; kk += 256) {
        const int k = colBase + kk + tid;
        double s0 = 0.0, s1 = 0.0, s2 = 0.0, s3 = 0.0;
#pragma unroll 4
        for (int d = 0; d < D_DIM; d += 4) {
            double f0 = (double)xs[d+0] - (double)E[(size_t)(d+0) * K_DIM + k];
            double f1 = (double)xs[d+1] - (double)E[(size_t)(d+1) * K_DIM + k];
            double f2 = (double)xs[d+2] - (double)E[(size_t)(d+2) * K_DIM + k];
            double f3 = (double)xs[d+3] - (double)E[(size_t)(d+3) * K_DIM + k];
            s0 = fma(f0, f0, s0); s1 = fma(f1, f1, s1);
            s2 = fma(f2, f2, s2); s3 = fma(f3, f3, s3);
        }
        double s = (s0 + s1) + (s2 + s3);
        if (s < best) { best = s; bi = k; }
    }

    __shared__ double bv[256];
    __shared__ int bix[256];
    bv[tid] = best; bix[tid] = bi;
    __syncthreads();
    if (tid == 0) {
        double b = bv[0]; int ix = bix[0];
        for (int t = 1; t < 256; ++t)
            if (bv[t] < b || (bv[t] == b && bix[t] < ix)) { b = bv[t]; ix = bix[t]; }
        t3b[sp * T3CAP + slot] = b;
        t3i[sp * T3CAP + slot] = ix;
    }
}

__global__ void merge3_kernel(const double* __restrict__ t3b,
                              const int* __restrict__ t3i,
                              const int* __restrict__ list3,
                              const int* __restrict__ count3,
                              int* __restrict__ idxf) {
    const int slot = blockIdx.x * 256 + threadIdx.x;
    const int cnt = min(*count3, T3CAP);
    if (slot >= cnt) return;
    double b = t3b[slot];
    int k = t3i[slot];
#pragma unroll
    for (int sp = 1; sp < NSPLIT3; ++sp) {
        double ob = t3b[sp * T3CAP + slot];
        int   ok = t3i[sp * T3CAP + slot];
        if (ob < b || (ob == b && ok < k)) { b = ob; k = ok; }
    }
    idxf[list3[slot]] = k;
}

// ---------------------------------------------------------------------------
// gather from transposed table: out[n][:] = ET[idx[n]][:]  (coalesced)
// ---------------------------------------------------------------------------
__global__ void gather2_kernel(const float* __restrict__ ET,
                               const int* __restrict__ idx,
                               float* __restrict__ out) {
    const int n  = blockIdx.x * 4 + (threadIdx.x >> 6);
    const int d4 = (threadIdx.x & 63) * 4;
    const int k  = idx[n];
    *reinterpret_cast<float4*>(&out[(size_t)n * D_DIM + d4]) =
        *reinterpret_cast<const float4*>(&ET[(size_t)k * D_DIM + d4]);
}

// strided fallback gather (no ET workspace)
__global__ void gather_kernel(const float* __restrict__ E,
                              const int* __restrict__ idx,
                              float* __restrict__ out) {
    const int n = blockIdx.x;
    const int d = threadIdx.x;
    const int k = idx[n];
    out[(size_t)n * D_DIM + d] = E[(size_t)d * K_DIM + k];
}

// ======================= fallback path (proven round-2) =====================
__global__ void fb_enorm_kernel(const float* __restrict__ E, float* __restrict__ enorm) {
    int k = blockIdx.x * 256 + threadIdx.x;
    float s = 0.0f;
#pragma unroll 8
    for (int d = 0; d < D_DIM; ++d) { float v = E[(size_t)d * K_DIM + k]; s = fmaf(v, v, s); }
    enorm[k] = s;
}

__launch_bounds__(256, 2)
__global__ void fb_dist_kernel(const float* __restrict__ X, const float* __restrict__ E,
                               const float* __restrict__ enorm,
                               int* __restrict__ idx_out, float* __restrict__ gap_out) {
    __shared__ float xT[D_DIM][64];
    __shared__ float es[64][64];
    const int tid = threadIdx.x;
    const int tx = tid & 15, ty = tid >> 4;
    const int rowBase = blockIdx.x * 64;
    {
        const int r = tid >> 2;
        const int d0 = (tid & 3) * 64;
        const float* xp = X + (size_t)(rowBase + r) * D_DIM + d0;
#pragma unroll
        for (int i = 0; i < 64; i += 4) {
            float4 v = *reinterpret_cast<const float4*>(xp + i);
            xT[d0+i+0][r]=v.x; xT[d0+i+1][r]=v.y; xT[d0+i+2][r]=v.z; xT[d0+i+3][r]=v.w;
        }
    }
    float bestVal[4], secVal[4]; int bestIdx[4];
#pragma unroll
    for (int i = 0; i < 4; ++i) { bestVal[i]=INFINITY; secVal[i]=INFINITY; bestIdx[i]=0; }
    for (int kc = 0; kc < K_DIM; kc += 64) {
        float acc[4][4];
#pragma unroll
        for (int i=0;i<4;++i)
#pragma unroll
            for (int j=0;j<4;++j) acc[i][j]=0.f;
        for (int dc = 0; dc < D_DIM; dc += 64) {
            __syncthreads();
#pragma unroll
            for (int dd = 0; dd < 64; dd += 16) {
                int d = dd + (tid >> 4);
                float4 v = *reinterpret_cast<const float4*>(
                    &E[(size_t)(dc+d)*K_DIM + kc + (tid&15)*4]);
                *reinterpret_cast<float4*>(&es[d][(tid&15)*4]) = v;
            }
            __syncthreads();
#pragma unroll 8
            for (int d = 0; d < 64; ++d) {
                float4 xv = *reinterpret_cast<const float4*>(&xT[dc+d][ty*4]);
                float4 ev = *reinterpret_cast<const float4*>(&es[d][tx*4]);
                float xr[4]={xv.x,xv.y,xv.z,xv.w}, ec[4]={ev.x,ev.y,ev.z,ev.w};
#pragma unroll
                for (int i=0;i<4;++i)
#pragma unroll
                    for (int j=0;j<4;++j) acc[i][j]=fmaf(xr[i],ec[j],acc[i][j]);
            }
        }
        float4 env = *reinterpret_cast<const float4*>(&enorm[kc + tx*4]);
        float en[4]={env.x,env.y,env.z,env.w};
#pragma unroll
        for (int j=0;j<4;++j) {
            int k = kc + tx*4 + j;
#pragma unroll
            for (int i=0;i<4;++i) {
                float s = fmaf(-2.0f, acc[i][j], en[j]);
                if (s < bestVal[i]) { secVal[i]=bestVal[i]; bestVal[i]=s; bestIdx[i]=k; }
                else if (s < secVal[i]) secVal[i]=s;
            }
        }
    }
#pragma unroll
    for (int off=8; off>=1; off>>=1) {
#pragma unroll
        for (int i=0;i<4;++i) {
            float oB=__shfl_xor(bestVal[i],off,16);
            int oI=__shfl_xor(bestIdx[i],off,16);
            float oS=__shfl_xor(secVal[i],off,16);
            float ms=fminf(fminf(secVal[i],oS),fmaxf(bestVal[i],oB));
            if (oB<bestVal[i] || (oB==bestVal[i] && oI<bestIdx[i])) { bestVal[i]=oB; bestIdx[i]=oI; }
            secVal[i]=ms;
        }
    }
    if (tx==0) {
#pragma unroll
        for (int i=0;i<4;++i) {
            idx_out[rowBase + ty*4 + i] = bestIdx[i];
            gap_out[rowBase + ty*4 + i] = secVal[i]-bestVal[i];
        }
    }
}

__launch_bounds__(256)
__global__ void fb_refine_kernel(const float* __restrict__ X, const float* __restrict__ E,
                                 const float* __restrict__ gap, int* __restrict__ idx) {
    const int n = blockIdx.x;
    if (gap[n] >= 0.0625f) return;
    __shared__ float xs[D_DIM];
    const int tid = threadIdx.x;
    xs[tid] = X[(size_t)n * D_DIM + tid];
    __syncthreads();
    double best = DBL_MAX; int bi = 0x7fffffff;
    for (int k = tid; k < K_DIM; k += 256) {
        double s0=0,s1=0,s2=0,s3=0;
#pragma unroll 4
        for (int d = 0; d < D_DIM; d += 4) {
            double f0=(double)xs[d+0]-(double)E[(size_t)(d+0)*K_DIM+k];
            double f1=(double)xs[d+1]-(double)E[(size_t)(d+1)*K_DIM+k];
            double f2=(double)xs[d+2]-(double)E[(size_t)(d+2)*K_DIM+k];
            double f3=(double)xs[d+3]-(double)E[(size_t)(d+3)*K_DIM+k];
            s0=fma(f0,f0,s0); s1=fma(f1,f1,s1); s2=fma(f2,f2,s2); s3=fma(f3,f3,s3);
        }
        double s=(s0+s1)+(s2+s3);
        if (s<best){best=s;bi=k;}
    }
    __shared__ double bv[256]; __shared__ int bix[256];
    bv[tid]=best; bix[tid]=bi;
    __syncthreads();
    if (tid==0) {
        double b=bv[0]; int ix=bix[0];
        for (int t=1;t<256;++t)
            if (bv[t]<b || (bv[t]==b && bix[t]<ix)) { b=bv[t]; ix=bix[t]; }
        idx[n]=ix;
    }
}

// ---------------------------------------------------------------------------
extern "C" void kernel_launch(void* const* d_in, const int* in_sizes, int n_in,
                              void* d_out, int out_size, void* d_ws, size_t ws_size,
                              hipStream_t stream) {
    const float* X = (const float*)d_in[0];
    const float* E = (const float*)d_in[1];
    float* out = (float*)d_out;
    char* ws = (char*)d_ws;

    // fast-path workspace layout
    const size_t o_nhen  = 0;                                       // K*4
    const size_t o_pb    = 32768;
    const size_t o_ps    = o_pb  + (size_t)KSPLIT * N_ROWS * 4;
    const size_t o_pi    = o_ps  + (size_t)KSPLIT * N_ROWS * 4;
    const size_t o_idx   = o_pi  + (size_t)KSPLIT * N_ROWS * 4;
    const size_t o_list  = o_idx + (size_t)N_ROWS * 4;
    const size_t o_count = o_list + (size_t)T2CAP * 4;              // count @+0, count3 @+4
    const size_t o_t2b   = o_count + 256;
    const size_t o_t2s   = o_t2b + (size_t)16 * T2CAP * 4;
    const size_t o_t2i   = o_t2s + (size_t)16 * T2CAP * 4;
    const size_t o_list3 = o_t2i + (size_t)16 * T2CAP * 4;
    const size_t o_t3b   = o_list3 + (size_t)T3CAP * 4;             // 8B-aligned
    const size_t o_t3i   = o_t3b + (size_t)NSPLIT3 * T3CAP * 8;
    const size_t o_x16   = o_t3i + (size_t)NSPLIT3 * T3CAP * 4;
    const size_t o_epack = o_x16 + (size_t)N_ROWS * D_DIM * 2;
    const size_t NEED_BASE = o_epack + (size_t)D_DIM * K_DIM * 2;
    const size_t o_et    = NEED_BASE;                               // optional ET
    const size_t NEED_FULL = o_et + (size_t)D_DIM * K_DIM * 4;

    if (ws_size >= NEED_BASE) {
        float*  nhen  = (float*) (ws + o_nhen);
        float*  p_b   = (float*) (ws + o_pb);
        float*  p_s   = (float*) (ws + o_ps);
        int*    p_i   = (int*)   (ws + o_pi);
        int*    idxf  = (int*)   (ws + o_idx);
        int*    list  = (int*)   (ws + o_list);
        int*    count = (int*)   (ws + o_count);
        int*    count3= (int*)   (ws + o_count + 4);
        float*  t2b   = (float*) (ws + o_t2b);
        float*  t2s   = (float*) (ws + o_t2s);
        int*    t2i   = (int*)   (ws + o_t2i);
        int*    list3 = (int*)   (ws + o_list3);
        double* t3b   = (double*)(ws + o_t3b);
        int*    t3i   = (int*)   (ws + o_t3i);
        f16*    X16   = (f16*)   (ws + o_x16);
        f16*    Epack = (f16*)   (ws + o_epack);
        float*  ET    = (float*) (ws + o_et);
        const bool haveET = ws_size >= NEED_FULL;

        convx_kernel<<<(N_ROWS * D_DIM / 8) / 256, 256, 0, stream>>>(X, X16);
        packe_kernel<<<(K_DIM / 16) * 8 * 64 / 256, 256, 0, stream>>>(E, Epack);
        nhen_kernel<<<K_DIM / 256, 256, 0, stream>>>(E, nhen);
        if (haveET)
            transpose_kernel<<<(K_DIM / 64) * (D_DIM / 64), 256, 0, stream>>>(E, ET);
        zero_counts_kernel<<<1, 1, 0, stream>>>(count, count3);
        pass1_kernel<<<(N_ROWS / 256) * KSPLIT, 256, 0, stream>>>(
            X16, Epack, nhen, p_b, p_s, p_i);
        merge_kernel<<<N_ROWS / 256, 256, 0, stream>>>(
            p_b, p_s, p_i, idxf, list, count);
        tier2_kernel<<<(T2CAP / 64) * 16, 256, 0, stream>>>(
            X, E, nhen, list, count, t2b, t2s, t2i);
        merge2_kernel<<<T2CAP / 256, 256, 0, stream>>>(
            t2b, t2s, t2i, list, count, idxf, list3, count3);
        tier3_kernel<<<T3CAP * NSPLIT3, 256, 0, stream>>>(
            X, E, list3, count3, t3b, t3i);
        merge3_kernel<<<T3CAP / 256, 256, 0, stream>>>(
            t3b, t3i, list3, count3, idxf);
        if (haveET)
            gather2_kernel<<<N_ROWS / 4, 256, 0, stream>>>(ET, idxf, out);
        else
            gather_kernel<<<N_ROWS, 256, 0, stream>>>(E, idxf, out);
    } else {
        float* enorm = (float*)ws;
        int*   idx   = (int*)(ws + 32768);
        float* gap   = (float*)(ws + 32768 + (size_t)N_ROWS * 4);
        fb_enorm_kernel<<<K_DIM / 256, 256, 0, stream>>>(E, enorm);
        fb_dist_kernel<<<N_ROWS / 64, 256, 0, stream>>>(X, E, enorm, idx, gap);
        fb_refine_kernel<<<N_ROWS, 256, 0, stream>>>(X, E, gap, idx);
        gather_kernel<<<N_ROWS, 256, 0, stream>>>(E, idx, out);
    }
}